// Round 2
// baseline (339.516 us; speedup 1.0000x reference)
//
#include <hip/hip_runtime.h>
#include <math.h>

// PPCALayer fused kernel, MI355X (gfx950) — register-resident tile version.
// x: [B=64, C=256, H*W=3136] fp32, weight: [3136, 15] fp32, out = x * gate.
//
// R2 change vs R1: no 64 KB LDS tile. Block = 1024 threads; each thread keeps
// its 4 channels x 4 spatials (16 floats) in registers, pre-sums its 4 channels
// (all within one 32-channel group), writes a 16 KB partial array to LDS,
// 8-way reduce -> 32-channel group sums -> gate; then multiplies register data
// by gate and stores. LDS/block ~18.5 KB -> 2 blocks/CU wave-limited (up to
// 32 waves/CU vs 8 in R1); LDS traffic cut ~4x.

constexpr int C_   = 256;
constexpr int HW_  = 3136;      // 56*56
constexpr int T_   = 64;        // spatial positions per block (49*64 = 3136)
constexpr int TPB_ = HW_ / T_;  // 49 tiles per image
constexpr int B_   = 64;

__global__ __launch_bounds__(1024, 8) void ppca_fused(
    const float* __restrict__ x, const float* __restrict__ wgt,
    float* __restrict__ out)
{
  __shared__ __align__(16) float P[64 * T_];  // 16 KB: partial sums [cq][spatial]
  __shared__ float S[8 * T_];                 // 2 KB: 32-ch group sums [g][spatial]
  __shared__ float gate[T_];

  const int blk = blockIdx.x;
  const int b   = blk / TPB_;
  const int til = blk - b * TPB_;
  const int sp0 = til * T_;
  const size_t base = (size_t)b * C_ * HW_ + sp0;
  const float* xb = x + base;
  float* ob = out + base;

  const int t   = threadIdx.x;   // 0..1023
  const int sp4 = t & 15;        // spatial quad: spatials 4*sp4 .. 4*sp4+3
  const int cq  = t >> 4;        // channel quad 0..63: channels 4*cq .. 4*cq+3

  // ---- Load: 4 float4 per thread, kept in registers for the whole kernel.
  // Per wave-instr: lanes 0..15 cover one contiguous 256B channel row (4 rows
  // per instr) — fully coalesced.
  float4 v[4];
  #pragma unroll
  for (int j = 0; j < 4; ++j)
    v[j] = *(const float4*)(xb + (size_t)(4 * cq + j) * HW_ + (sp4 << 2));

  // ---- In-register pre-reduce: this thread's 4 channels all lie in the same
  // 32-channel group (g = cq>>3). One float4 partial per thread.
  float4 p;
  p.x = (v[0].x + v[1].x) + (v[2].x + v[3].x);
  p.y = (v[0].y + v[1].y) + (v[2].y + v[3].y);
  p.z = (v[0].z + v[1].z) + (v[2].z + v[3].z);
  p.w = (v[0].w + v[1].w) + (v[2].w + v[3].w);
  *(float4*)(&P[cq * T_ + (sp4 << 2)]) = p;   // b128, conflict-free pattern
  __syncthreads();

  // ---- 8-way reduce across channel quads -> 32-channel group sums.
  // 512 threads: g = t>>6 (group 0..7), s = t&63 (spatial). Bank: s%32,
  // lanes s and s+32 alias (2-way = free).
  if (t < 512) {
    const int g = t >> 6;
    const int s = t & 63;
    float sum = 0.f;
    #pragma unroll
    for (int k = 0; k < 8; ++k) sum += P[(8 * g + k) * T_ + s];
    S[g * T_ + s] = sum;
  }
  __syncthreads();

  // ---- Gate: wave 0 computes the 64 gates (lane = spatial).
  if (t < T_) {
    float Sg[8];
    #pragma unroll
    for (int g = 0; g < 8; ++g) Sg[g] = S[g * T_ + t];
    float p64[4];
    #pragma unroll
    for (int j = 0; j < 4; ++j) p64[j] = Sg[2 * j] + Sg[2 * j + 1];
    const float p128a = p64[0] + p64[1];
    const float p128b = p64[2] + p64[3];
    const float tot   = p128a + p128b;

    // feats per SCALES=(1,2,4,8): [mean256, mean128 x2, mean64 x4, mean32 x8]
    float f[15];
    f[0] = tot * (1.f / 256.f);
    f[1] = p128a * (1.f / 128.f);
    f[2] = p128b * (1.f / 128.f);
    #pragma unroll
    for (int j = 0; j < 4; ++j) f[3 + j] = p64[j] * (1.f / 64.f);
    #pragma unroll
    for (int g = 0; g < 8; ++g) f[7 + g] = Sg[g] * (1.f / 32.f);

    float m = 0.f;
    #pragma unroll
    for (int i = 0; i < 15; ++i) m += f[i];
    m *= (1.f / 15.f);
    float var = 0.f;
    #pragma unroll
    for (int i = 0; i < 15; ++i) { const float d = f[i] - m; var += d * d; }
    var *= (1.f / 15.f);
    const float inv = 1.f / sqrtf(var);

    const float* wp = wgt + (size_t)(sp0 + t) * 15;
    float z = 0.f;
    #pragma unroll
    for (int i = 0; i < 15; ++i) z += (f[i] - m) * wp[i];
    z *= inv;
    gate[t] = 1.f / (1.f + __expf(-z));
  }
  __syncthreads();

  // ---- Multiply register data by gate, store (coalesced float4).
  const float4 g4 = *(const float4*)(&gate[sp4 << 2]);
  #pragma unroll
  for (int j = 0; j < 4; ++j) {
    float4 vv = v[j];
    vv.x *= g4.x; vv.y *= g4.y; vv.z *= g4.z; vv.w *= g4.w;
    *(float4*)(ob + (size_t)(4 * cq + j) * HW_ + (sp4 << 2)) = vv;
  }
}

extern "C" void kernel_launch(void* const* d_in, const int* in_sizes, int n_in,
                              void* d_out, int out_size, void* d_ws, size_t ws_size,
                              hipStream_t stream) {
  const float* x = (const float*)d_in[0];      // [64,256,3136] fp32
  const float* w = (const float*)d_in[1];      // [3136,15] fp32
  float* out = (float*)d_out;                  // [64,256,3136] fp32
  (void)in_sizes; (void)n_in; (void)out_size; (void)d_ws; (void)ws_size;

  dim3 grid(B_ * TPB_);   // 3136 blocks
  dim3 block(1024);
  ppca_fused<<<grid, block, 0, stream>>>(x, w, out);
}